// Round 11
// baseline (285.286 us; speedup 1.0000x reference)
//
#include <hip/hip_runtime.h>
#include <math.h>

#define PS 4224          // partial stride (floats): 64*64 acc + 64 m + 64 l
#define CNT_OFF 1622016  // 48*8*PS floats; counters live after the partials
#define NEG -10000.f

typedef short short8v __attribute__((ext_vector_type(8)));
typedef float f32x4  __attribute__((ext_vector_type(4)));

// LDS: 4 regions, 64 rows x 64 ushorts (128B rows, XOR-swizzled 16B slots)
#define KHo  0
#define KLo  4096
#define VTHo 8192
#define VTLo 12288
#define LDS_TOT 16384    // ushorts = 32 KB

__device__ __forceinline__ unsigned au(float x){ return __float_as_uint(x); }
__device__ __forceinline__ float    af(unsigned x){ return __uint_as_float(x); }

// split 4 floats into packed-bf16 hi pair-words and lo pair-words (truncate; lo compensates)
__device__ __forceinline__ void pack4(float a, float b, float c, float d,
                                      unsigned &h01, unsigned &h23,
                                      unsigned &l01, unsigned &l23) {
    unsigned u0=au(a), u1=au(b), u2=au(c), u3=au(d);
    h01 = __builtin_amdgcn_perm(u1, u0, 0x07060302);   // [bf16(b) | bf16(a)]
    h23 = __builtin_amdgcn_perm(u3, u2, 0x07060302);
    float r0 = a - af(u0 & 0xffff0000u);
    float r1 = b - af(u1 & 0xffff0000u);
    float r2 = c - af(u2 & 0xffff0000u);
    float r3 = d - af(u3 & 0xffff0000u);
    l01 = __builtin_amdgcn_perm(au(r1), au(r0), 0x07060302);
    l23 = __builtin_amdgcn_perm(au(r3), au(r2), 0x07060302);
}

// ushort index into a 64x64 region with XOR-swizzled 16B slots
__device__ __forceinline__ int swz(int row, int colus) {
    return row*64 + (((colus>>3) ^ (row&7))<<3) + (colus&7);
}

#define MFMA(a,b,c) __builtin_amdgcn_mfma_f32_16x16x32_bf16((a),(b),(c),0,0,0)

union FragU { unsigned u[4]; short8v s; };

__device__ __forceinline__ void tile_of(bool partial, bool isMid, int m, int seg,
                                        int r0, int r1, int r2i, int t,
                                        int &blk, int &ty) {
    if (partial)     { blk = seg*8 + t; ty = 0; }
    else if (isMid) {
        if (t == 0)      { blk = 0;       ty = 0; }
        else if (t <= 3) { blk = m-2 + t; ty = t; }
        else if (t <= 6) { blk = (t==4)?r0:((t==5)?r1:r2i); ty = 4; }
        else             { blk = 63;      ty = 0; }
    } else {
        if (t < 4) { blk = (m==1) ? ((t<3)? t : 63) : ((t==0)? 0 : 60+t); ty = 0; }
        else       { blk = (t==4)?r0:((t==5)?r1:r2i); ty = 4; }
    }
}

__global__ __launch_bounds__(256, 4) void bigbird_attn(
    const float* __restrict__ Qg, const float* __restrict__ Kg, const float* __restrict__ Vg,
    const float* __restrict__ band_mask, const float* __restrict__ from_mask,
    const float* __restrict__ to_mask, const float* __restrict__ fbm,
    const float* __restrict__ tbm, const int* __restrict__ rand_attn,
    float* __restrict__ out, float* __restrict__ ws)
{
    const int H = 12, S = 4096;
    __shared__ __align__(16) unsigned short lds[LDS_TOT];
    __shared__ int lastFlag;

    const int tid  = threadIdx.x;
    const int w    = tid >> 6;        // wave 0..3 -> q rows [16w,16w+16)
    const int lane = tid & 63;
    const int l15  = lane & 15;       // q-row offset (B-frag), LDS frag row offset
    const int l4   = lane >> 4;       // 0..3: k-slice / C-row quad

    // ---- decode: XCD-chunked (1872 = 8 * 234, 234 = 3 heads * 78 WGs) ----
    int wg0 = blockIdx.x;
    int u   = (wg0 & 7) * 234 + (wg0 >> 3);   // bijective: nwg % 8 == 0
    int head = u / 78;                        // 0..23
    int within = u - head*78;                 // 0..77
    int b = head / 12, h = head - (head/12)*12;
    int m, seg = 0;
    bool partial;
    if (within < 16) { partial = true;  m = (within >= 8) ? 63 : 0; seg = within & 7; }
    else             { partial = false; m = within - 15; }          // 1..62

    const long bh = (long)b*H + h;
    const float* Qb = Qg + (bh*S + (long)m*64)*64;
    const float* Kb = Kg + bh*S*64;
    const float* Vb = Vg + bh*S*64;

    const bool isMid = (m >= 2) && (m <= 61);
    int nt_cnt;
    int r0 = 1, r1 = 1, r2i = 1;
    if (partial) nt_cnt = 8;
    else {
        const int* ra = rand_attn + (bh*62 + (m-1))*3;
        r0 = ra[0]; r1 = ra[1]; r2i = ra[2];
        nt_cnt = isMid ? 8 : 7;
    }

    // ---- Q fragments straight to registers (B-operand; no LDS) ----
    short8v qhf[2], qlf[2];
    #pragma unroll
    for (int ks = 0; ks < 2; ++ks) {
        const float* qp = &Qb[(16*w + l15)*64 + l4*8 + 32*ks];
        float4 a = *(const float4*)qp;
        float4 b2 = *(const float4*)(qp + 4);
        FragU fh, fl;
        pack4(a.x,a.y,a.z,a.w, fh.u[0],fh.u[1], fl.u[0],fl.u[1]);
        pack4(b2.x,b2.y,b2.z,b2.w, fh.u[2],fh.u[3], fl.u[2],fl.u[3]);
        qhf[ks] = fh.s; qlf[ks] = fl.s;
    }

    // staging thread mapping
    const int kr0 = tid >> 4;          // K rows kr0 + 16c
    const int kc  = (tid & 15) << 2;   // K col (floats/ushorts)
    const int vd  = tid & 63;          // V: d row
    const int vkg = tid >> 6;          // V: key group

    // ---- prefetch tile 0 ----
    int blkN, tyN;
    tile_of(partial, isMid, m, seg, r0, r1, r2i, 0, blkN, tyN);
    float4 kreg[4];
    float  vreg[16];
    {
        const float* Kt = Kb + (long)blkN*4096;
        const float* Vt0 = Vb + (long)blkN*4096;
        #pragma unroll
        for (int c = 0; c < 4; ++c) kreg[c] = *(const float4*)&Kt[(kr0+16*c)*64 + kc];
        #pragma unroll
        for (int p = 0; p < 4; ++p)
            #pragma unroll
            for (int i = 0; i < 4; ++i)
                vreg[p*4+i] = Vt0[(p*16 + vkg*4 + i)*64 + vd];
    }

    f32x4 oacc[4];
    #pragma unroll
    for (int i = 0; i < 4; ++i) oacc[i] = (f32x4){0.f,0.f,0.f,0.f};
    float mrow = -INFINITY, lrow = 0.f;

    for (int t = 0; t < nt_cnt; ++t) {
        const int blk = blkN, ty = tyN;

        __syncthreads();   // prev tile's MFMAs done reading LDS

        // ---- stage K (rows) and V^T (keys along rows of d) from regs ----
        #pragma unroll
        for (int c = 0; c < 4; ++c) {
            FragU fh, fl;
            pack4(kreg[c].x,kreg[c].y,kreg[c].z,kreg[c].w, fh.u[0],fh.u[1], fl.u[0],fl.u[1]);
            int o = swz(kr0+16*c, kc);
            *(uint2*)&lds[KHo + o] = make_uint2(fh.u[0],fh.u[1]);
            *(uint2*)&lds[KLo + o] = make_uint2(fl.u[0],fl.u[1]);
        }
        #pragma unroll
        for (int p = 0; p < 4; ++p) {
            FragU fh, fl;
            pack4(vreg[p*4+0],vreg[p*4+1],vreg[p*4+2],vreg[p*4+3],
                  fh.u[0],fh.u[1], fl.u[0],fl.u[1]);
            int o = swz(vd, p*16 + vkg*4);
            *(uint2*)&lds[VTHo + o] = make_uint2(fh.u[0],fh.u[1]);
            *(uint2*)&lds[VTLo + o] = make_uint2(fl.u[0],fl.u[1]);
        }
        __syncthreads();   // staging visible

        // ---- prefetch next tile into regs (latency hides under compute) ----
        if (t + 1 < nt_cnt) {
            tile_of(partial, isMid, m, seg, r0, r1, r2i, t+1, blkN, tyN);
            const float* Kt = Kb + (long)blkN*4096;
            const float* Vt0 = Vb + (long)blkN*4096;
            #pragma unroll
            for (int c = 0; c < 4; ++c) kreg[c] = *(const float4*)&Kt[(kr0+16*c)*64 + kc];
            #pragma unroll
            for (int p = 0; p < 4; ++p)
                #pragma unroll
                for (int i = 0; i < 4; ++i)
                    vreg[p*4+i] = Vt0[(p*16 + vkg*4 + i)*64 + vd];
        }

        // ---- mask addend (key = 16nt + 4*l4 + reg, q = 16w + l15) ----
        f32x4 addv[4];
        if (ty == 0) {
            #pragma unroll
            for (int nt = 0; nt < 4; ++nt) {
                f32x4 tv = *(const f32x4*)&to_mask[(long)b*S + blk*64 + 16*nt + 4*l4];
                addv[nt] = (1.f - tv) * NEG;
            }
        } else if (ty <= 3) {
            const float* bq = band_mask + ((long)(b*60 + (m-2)))*64*192
                              + (16*w + l15)*192 + (ty-1)*64;
            #pragma unroll
            for (int nt = 0; nt < 4; ++nt) {
                f32x4 tv = *(const f32x4*)&bq[16*nt + 4*l4];
                addv[nt] = (1.f - tv) * NEG;
            }
        } else {
            float fq = fbm[((long)b*64 + m)*64 + 16*w + l15];
            #pragma unroll
            for (int nt = 0; nt < 4; ++nt) {
                f32x4 tv = *(const f32x4*)&tbm[((long)b*64 + blk)*64 + 16*nt + 4*l4];
                addv[nt] = (1.f - fq*tv) * NEG;
            }
        }

        // ---- QK^T swapped: S^T[key][q]; lane holds 16 scores of ONE q row ----
        f32x4 sacc[4];
        #pragma unroll
        for (int nt = 0; nt < 4; ++nt) sacc[nt] = (f32x4){0.f,0.f,0.f,0.f};
        #pragma unroll
        for (int ks = 0; ks < 2; ++ks) {
            const int col = l4*8 + 32*ks;
            #pragma unroll
            for (int nt = 0; nt < 4; ++nt) {
                int o = swz(16*nt + l15, col);
                short8v kh = *(const short8v*)&lds[KHo + o];
                short8v kl = *(const short8v*)&lds[KLo + o];
                sacc[nt] = MFMA(kh, qhf[ks], sacc[nt]);
                sacc[nt] = MFMA(kl, qhf[ks], sacc[nt]);
                sacc[nt] = MFMA(kh, qlf[ks], sacc[nt]);
            }
        }

        // ---- online softmax: reduce over own 16 + l4-group (xor 16,32) ----
        f32x4 sr[4];
        float mx = -INFINITY;
        #pragma unroll
        for (int nt = 0; nt < 4; ++nt) {
            sr[nt] = sacc[nt]*0.125f + addv[nt];
            mx = fmaxf(mx, fmaxf(fmaxf(sr[nt][0], sr[nt][1]), fmaxf(sr[nt][2], sr[nt][3])));
        }
        mx = fmaxf(mx, __shfl_xor(mx, 16));
        mx = fmaxf(mx, __shfl_xor(mx, 32));
        float mn = fmaxf(mrow, mx);
        float al = __expf(mrow - mn);
        float ls = 0.f;
        f32x4 pq[4];
        #pragma unroll
        for (int nt = 0; nt < 4; ++nt) {
            pq[nt][0] = __expf(sr[nt][0] - mn);
            pq[nt][1] = __expf(sr[nt][1] - mn);
            pq[nt][2] = __expf(sr[nt][2] - mn);
            pq[nt][3] = __expf(sr[nt][3] - mn);
            ls += pq[nt][0] + pq[nt][1] + pq[nt][2] + pq[nt][3];
        }
        ls += __shfl_xor(ls, 16);
        ls += __shfl_xor(ls, 32);
        lrow = lrow*al + ls;
        mrow = mn;

        // ---- pack P quads to bf16 hi/lo (in regs) ----
        unsigned ph01[4], ph23[4], pl01[4], pl23[4];
        #pragma unroll
        for (int nt = 0; nt < 4; ++nt)
            pack4(pq[nt][0],pq[nt][1],pq[nt][2],pq[nt][3],
                  ph01[nt],ph23[nt], pl01[nt],pl23[nt]);

        // ---- redistribute P^T -> PV B-frag via shfl_xor within l4-group ----
        short8v pbh[2], pbl[2];
        #pragma unroll
        for (int ks = 0; ks < 2; ++ks) {
            const int loNT = 2*ks, hiNT = 2*ks+1;
            const bool up = (l4 & 2);
            unsigned aH0 = up ? ph01[hiNT] : ph01[loNT];
            unsigned aH1 = up ? ph23[hiNT] : ph23[loNT];
            unsigned aL0 = up ? pl01[hiNT] : pl01[loNT];
            unsigned aL1 = up ? pl23[hiNT] : pl23[loNT];
            unsigned sH0 = up ? ph01[loNT] : ph01[hiNT];
            unsigned sH1 = up ? ph23[loNT] : ph23[hiNT];
            unsigned sL0 = up ? pl01[loNT] : pl01[hiNT];
            unsigned sL1 = up ? pl23[loNT] : pl23[hiNT];
            unsigned x16H0 = __shfl_xor((int)aH0, 16), x16H1 = __shfl_xor((int)aH1, 16);
            unsigned x16L0 = __shfl_xor((int)aL0, 16), x16L1 = __shfl_xor((int)aL1, 16);
            unsigned x32H0 = __shfl_xor((int)sH0, 32), x32H1 = __shfl_xor((int)sH1, 32);
            unsigned x32L0 = __shfl_xor((int)sL0, 32), x32L1 = __shfl_xor((int)sL1, 32);
            unsigned x48H0 = __shfl_xor((int)sH0, 48), x48H1 = __shfl_xor((int)sH1, 48);
            unsigned x48L0 = __shfl_xor((int)sL0, 48), x48L1 = __shfl_xor((int)sL1, 48);
            FragU fh, fl;
            fh.u[0] = (l4==0)?aH0 : (l4==1)?x48H0 : (l4==2)?x32H0 : x16H0;
            fh.u[1] = (l4==0)?aH1 : (l4==1)?x48H1 : (l4==2)?x32H1 : x16H1;
            fh.u[2] = (l4==0)?x16H0 : (l4==1)?x32H0 : (l4==2)?x48H0 : aH0;
            fh.u[3] = (l4==0)?x16H1 : (l4==1)?x32H1 : (l4==2)?x48H1 : aH1;
            fl.u[0] = (l4==0)?aL0 : (l4==1)?x48L0 : (l4==2)?x32L0 : x16L0;
            fl.u[1] = (l4==0)?aL1 : (l4==1)?x48L1 : (l4==2)?x32L1 : x16L1;
            fl.u[2] = (l4==0)?x16L0 : (l4==1)?x32L0 : (l4==2)?x48L0 : aL0;
            fl.u[3] = (l4==0)?x16L1 : (l4==1)?x32L1 : (l4==2)?x48L1 : aL1;
            pbh[ks] = fh.s; pbl[ks] = fl.s;
        }

        // ---- rescale, then PV: O^T[d][q] = Vt x P ----
        #pragma unroll
        for (int dnt = 0; dnt < 4; ++dnt) oacc[dnt] *= al;
        #pragma unroll
        for (int ks = 0; ks < 2; ++ks) {
            const int col = l4*8 + 32*ks;
            #pragma unroll
            for (int dnt = 0; dnt < 4; ++dnt) {
                int o = swz(16*dnt + l15, col);
                short8v vh = *(const short8v*)&lds[VTHo + o];
                short8v vl = *(const short8v*)&lds[VTLo + o];
                oacc[dnt] = MFMA(vh, pbh[ks], oacc[dnt]);
                oacc[dnt] = MFMA(vl, pbh[ks], oacc[dnt]);
                oacc[dnt] = MFMA(vh, pbl[ks], oacc[dnt]);
            }
        }
    }

    // ---- epilogue: lane owns q = 16w + l15, d = 16dnt + 4*l4 + 0..3 ----
    const int q64 = 16*w + l15;
    if (partial) {
        const int rowIdx = (int)(bh*2 + (m ? 1 : 0));
        float* P = ws + ((long)rowIdx*8 + seg) * PS;
        #pragma unroll
        for (int dnt = 0; dnt < 4; ++dnt)
            *(f32x4*)&P[q64*64 + 16*dnt + 4*l4] = oacc[dnt];
        if (l4 == 0) { P[4096 + q64] = mrow; P[4160 + q64] = lrow; }

        // ---- split-K last-arriver merge (replaces second kernel) ----
        __threadfence();
        if (tid == 0) {
            int* cnt = (int*)(ws + CNT_OFF);
            int old = atomicAdd(&cnt[rowIdx], 1);
            lastFlag = (old == 7);
        }
        __syncthreads();
        if (lastFlag) {
            __threadfence();   // acquire other WGs' partials
            const float* base = ws + (long)rowIdx * 8 * PS;
            int q  = tid >> 2;
            int dd = (tid & 3) << 4;
            float msg[8], lsg[8];
            float M = -INFINITY;
            #pragma unroll
            for (int s = 0; s < 8; ++s) {
                msg[s] = base[s*PS + 4096 + q];
                lsg[s] = base[s*PS + 4160 + q];
                M = fmaxf(M, msg[s]);
            }
            float L = 0.f, wv[8];
            #pragma unroll
            for (int s = 0; s < 8; ++s) { wv[s] = __expf(msg[s] - M); L += wv[s]*lsg[s]; }
            int qg = m*64 + q;
            float sc = from_mask[(long)b*S + qg] / L;
            #pragma unroll
            for (int c = 0; c < 4; ++c) {
                float4 o = make_float4(0.f, 0.f, 0.f, 0.f);
                #pragma unroll
                for (int s = 0; s < 8; ++s) {
                    float4 a = *(const float4*)&base[s*PS + q*64 + dd + 4*c];
                    o.x += wv[s]*a.x; o.y += wv[s]*a.y; o.z += wv[s]*a.z; o.w += wv[s]*a.w;
                }
                o.x *= sc; o.y *= sc; o.z *= sc; o.w *= sc;
                *(float4*)&out[((long)((long)b*S + qg)*H + h)*64 + dd + 4*c] = o;
            }
        }
    } else {
        int qg = m*64 + q64;
        float scn = (1.f / lrow) * from_mask[(long)b*S + qg];
        #pragma unroll
        for (int dnt = 0; dnt < 4; ++dnt) {
            f32x4 o = oacc[dnt] * scn;
            *(f32x4*)&out[((long)((long)b*S + qg)*H + h)*64 + 16*dnt + 4*l4] = o;
        }
    }
}

extern "C" void kernel_launch(void* const* d_in, const int* in_sizes, int n_in,
                              void* d_out, int out_size, void* d_ws, size_t ws_size,
                              hipStream_t stream) {
    const float* q   = (const float*)d_in[0];
    const float* k   = (const float*)d_in[1];
    const float* v   = (const float*)d_in[2];
    const float* bm  = (const float*)d_in[3];
    const float* fm  = (const float*)d_in[4];
    const float* tm  = (const float*)d_in[5];
    const float* fbm = (const float*)d_in[6];
    const float* tbm = (const float*)d_in[7];
    const int*   ra  = (const int*)d_in[8];
    float* out = (float*)d_out;
    float* ws  = (float*)d_ws;   // 48*8*PS floats partials + 48 int counters

    hipMemsetAsync((char*)d_ws + (size_t)CNT_OFF*4, 0, 48*sizeof(int), stream);
    bigbird_attn<<<dim3(1872), dim3(256), 0, stream>>>(q, k, v, bm, fm, tm, fbm, tbm, ra, out, ws);
}

// Round 13
// 260.708 us; speedup vs baseline: 1.0943x; 1.0943x over previous
//
#include <hip/hip_runtime.h>
#include <math.h>

#define PS 4224          // partial stride (floats): 64*64 acc + 64 m + 64 l
#define CNT_OFF 1622016  // 48*8*PS floats; counters live after the partials
#define NEG -10000.f

typedef short short8v __attribute__((ext_vector_type(8)));
typedef float f32x4  __attribute__((ext_vector_type(4)));

// LDS: 4 regions, 64 rows x 64 ushorts (128B rows, XOR-swizzled 16B slots)
#define KHo  0
#define KLo  4096
#define VTHo 8192
#define VTLo 12288
#define LDS_TOT 16384    // ushorts = 32 KB

__device__ __forceinline__ unsigned au(float x){ return __float_as_uint(x); }
__device__ __forceinline__ float    af(unsigned x){ return __uint_as_float(x); }

// split 4 floats into packed-bf16 hi pair-words and lo pair-words (truncate; lo compensates)
__device__ __forceinline__ void pack4(float a, float b, float c, float d,
                                      unsigned &h01, unsigned &h23,
                                      unsigned &l01, unsigned &l23) {
    unsigned u0=au(a), u1=au(b), u2=au(c), u3=au(d);
    h01 = __builtin_amdgcn_perm(u1, u0, 0x07060302);   // [bf16(b) | bf16(a)]
    h23 = __builtin_amdgcn_perm(u3, u2, 0x07060302);
    float r0 = a - af(u0 & 0xffff0000u);
    float r1 = b - af(u1 & 0xffff0000u);
    float r2 = c - af(u2 & 0xffff0000u);
    float r3 = d - af(u3 & 0xffff0000u);
    l01 = __builtin_amdgcn_perm(au(r1), au(r0), 0x07060302);
    l23 = __builtin_amdgcn_perm(au(r3), au(r2), 0x07060302);
}

// ushort index into a 64x64 region with XOR-swizzled 16B slots
__device__ __forceinline__ int swz(int row, int colus) {
    return row*64 + (((colus>>3) ^ (row&7))<<3) + (colus&7);
}

#define MFMA(a,b,c) __builtin_amdgcn_mfma_f32_16x16x32_bf16((a),(b),(c),0,0,0)

union FragU { unsigned u[4]; short8v s; };

__device__ __forceinline__ void tile_of(bool partial, bool isMid, int m, int seg,
                                        int r0, int r1, int r2i, int t,
                                        int &blk, int &ty) {
    if (partial)     { blk = seg*8 + t; ty = 0; }
    else if (isMid) {
        if (t == 0)      { blk = 0;       ty = 0; }
        else if (t <= 3) { blk = m-2 + t; ty = t; }
        else if (t <= 6) { blk = (t==4)?r0:((t==5)?r1:r2i); ty = 4; }
        else             { blk = 63;      ty = 0; }
    } else {
        if (t < 4) { blk = (m==1) ? ((t<3)? t : 63) : ((t==0)? 0 : 60+t); ty = 0; }
        else       { blk = (t==4)?r0:((t==5)?r1:r2i); ty = 4; }
    }
}

// block=256, min 3 waves/EU: VGPR cap 128 (compiler used 80 in r8, no spill).
// (256,4) capped VGPR at 64 -> ~35MB scratch spill traffic, attn 117->195us (r11).
__global__ __launch_bounds__(256, 3) void bigbird_attn(
    const float* __restrict__ Qg, const float* __restrict__ Kg, const float* __restrict__ Vg,
    const float* __restrict__ band_mask, const float* __restrict__ from_mask,
    const float* __restrict__ to_mask, const float* __restrict__ fbm,
    const float* __restrict__ tbm, const int* __restrict__ rand_attn,
    float* __restrict__ out, float* __restrict__ ws)
{
    const int H = 12, S = 4096;
    __shared__ __align__(16) unsigned short lds[LDS_TOT];
    __shared__ int lastFlag;

    const int tid  = threadIdx.x;
    const int w    = tid >> 6;        // wave 0..3 -> q rows [16w,16w+16)
    const int lane = tid & 63;
    const int l15  = lane & 15;       // q-row offset (B-frag), LDS frag row offset
    const int l4   = lane >> 4;       // 0..3: k-slice / C-row quad

    // ---- decode: XCD-chunked (1872 = 8 * 234, 234 = 3 heads * 78 WGs) ----
    int wg0 = blockIdx.x;
    int u   = (wg0 & 7) * 234 + (wg0 >> 3);   // bijective: nwg % 8 == 0
    int head = u / 78;                        // 0..23
    int within = u - head*78;                 // 0..77
    int b = head / 12, h = head - (head/12)*12;
    int m, seg = 0;
    bool partial;
    if (within < 16) { partial = true;  m = (within >= 8) ? 63 : 0; seg = within & 7; }
    else             { partial = false; m = within - 15; }          // 1..62

    const long bh = (long)b*H + h;
    const float* Qb = Qg + (bh*S + (long)m*64)*64;
    const float* Kb = Kg + bh*S*64;
    const float* Vb = Vg + bh*S*64;

    const bool isMid = (m >= 2) && (m <= 61);
    int nt_cnt;
    int r0 = 1, r1 = 1, r2i = 1;
    if (partial) nt_cnt = 8;
    else {
        const int* ra = rand_attn + (bh*62 + (m-1))*3;
        r0 = ra[0]; r1 = ra[1]; r2i = ra[2];
        nt_cnt = isMid ? 8 : 7;
    }

    // ---- Q fragments straight to registers (B-operand; no LDS) ----
    short8v qhf[2], qlf[2];
    #pragma unroll
    for (int ks = 0; ks < 2; ++ks) {
        const float* qp = &Qb[(16*w + l15)*64 + l4*8 + 32*ks];
        float4 a = *(const float4*)qp;
        float4 b2 = *(const float4*)(qp + 4);
        FragU fh, fl;
        pack4(a.x,a.y,a.z,a.w, fh.u[0],fh.u[1], fl.u[0],fl.u[1]);
        pack4(b2.x,b2.y,b2.z,b2.w, fh.u[2],fh.u[3], fl.u[2],fl.u[3]);
        qhf[ks] = fh.s; qlf[ks] = fl.s;
    }

    // staging thread mapping
    const int kr0 = tid >> 4;          // K rows kr0 + 16c
    const int kc  = (tid & 15) << 2;   // K col (floats/ushorts)
    const int vd  = tid & 63;          // V: d row
    const int vkg = tid >> 6;          // V: key group

    // ---- prefetch tile 0 ----
    int blkN, tyN;
    tile_of(partial, isMid, m, seg, r0, r1, r2i, 0, blkN, tyN);
    float4 kreg[4];
    float  vreg[16];
    {
        const float* Kt = Kb + (long)blkN*4096;
        const float* Vt0 = Vb + (long)blkN*4096;
        #pragma unroll
        for (int c = 0; c < 4; ++c) kreg[c] = *(const float4*)&Kt[(kr0+16*c)*64 + kc];
        #pragma unroll
        for (int p = 0; p < 4; ++p)
            #pragma unroll
            for (int i = 0; i < 4; ++i)
                vreg[p*4+i] = Vt0[(p*16 + vkg*4 + i)*64 + vd];
    }

    f32x4 oacc[4];
    #pragma unroll
    for (int i = 0; i < 4; ++i) oacc[i] = (f32x4){0.f,0.f,0.f,0.f};
    float mrow = -INFINITY, lrow = 0.f;

    for (int t = 0; t < nt_cnt; ++t) {
        const int blk = blkN, ty = tyN;

        __syncthreads();   // prev tile's MFMAs done reading LDS

        // ---- stage K (rows) and V^T (keys along rows of d) from regs ----
        #pragma unroll
        for (int c = 0; c < 4; ++c) {
            FragU fh, fl;
            pack4(kreg[c].x,kreg[c].y,kreg[c].z,kreg[c].w, fh.u[0],fh.u[1], fl.u[0],fl.u[1]);
            int o = swz(kr0+16*c, kc);
            *(uint2*)&lds[KHo + o] = make_uint2(fh.u[0],fh.u[1]);
            *(uint2*)&lds[KLo + o] = make_uint2(fl.u[0],fl.u[1]);
        }
        #pragma unroll
        for (int p = 0; p < 4; ++p) {
            FragU fh, fl;
            pack4(vreg[p*4+0],vreg[p*4+1],vreg[p*4+2],vreg[p*4+3],
                  fh.u[0],fh.u[1], fl.u[0],fl.u[1]);
            int o = swz(vd, p*16 + vkg*4);
            *(uint2*)&lds[VTHo + o] = make_uint2(fh.u[0],fh.u[1]);
            *(uint2*)&lds[VTLo + o] = make_uint2(fl.u[0],fl.u[1]);
        }
        __syncthreads();   // staging visible

        // ---- prefetch next tile into regs (latency hides under compute) ----
        if (t + 1 < nt_cnt) {
            tile_of(partial, isMid, m, seg, r0, r1, r2i, t+1, blkN, tyN);
            const float* Kt = Kb + (long)blkN*4096;
            const float* Vt0 = Vb + (long)blkN*4096;
            #pragma unroll
            for (int c = 0; c < 4; ++c) kreg[c] = *(const float4*)&Kt[(kr0+16*c)*64 + kc];
            #pragma unroll
            for (int p = 0; p < 4; ++p)
                #pragma unroll
                for (int i = 0; i < 4; ++i)
                    vreg[p*4+i] = Vt0[(p*16 + vkg*4 + i)*64 + vd];
        }

        // ---- mask addend (key = 16nt + 4*l4 + reg, q = 16w + l15) ----
        f32x4 addv[4];
        if (ty == 0) {
            #pragma unroll
            for (int nt = 0; nt < 4; ++nt) {
                f32x4 tv = *(const f32x4*)&to_mask[(long)b*S + blk*64 + 16*nt + 4*l4];
                addv[nt] = (1.f - tv) * NEG;
            }
        } else if (ty <= 3) {
            const float* bq = band_mask + ((long)(b*60 + (m-2)))*64*192
                              + (16*w + l15)*192 + (ty-1)*64;
            #pragma unroll
            for (int nt = 0; nt < 4; ++nt) {
                f32x4 tv = *(const f32x4*)&bq[16*nt + 4*l4];
                addv[nt] = (1.f - tv) * NEG;
            }
        } else {
            float fq = fbm[((long)b*64 + m)*64 + 16*w + l15];
            #pragma unroll
            for (int nt = 0; nt < 4; ++nt) {
                f32x4 tv = *(const f32x4*)&tbm[((long)b*64 + blk)*64 + 16*nt + 4*l4];
                addv[nt] = (1.f - fq*tv) * NEG;
            }
        }

        // ---- QK^T swapped: S^T[key][q]; lane holds 16 scores of ONE q row ----
        f32x4 sacc[4];
        #pragma unroll
        for (int nt = 0; nt < 4; ++nt) sacc[nt] = (f32x4){0.f,0.f,0.f,0.f};
        #pragma unroll
        for (int ks = 0; ks < 2; ++ks) {
            const int col = l4*8 + 32*ks;
            #pragma unroll
            for (int nt = 0; nt < 4; ++nt) {
                int o = swz(16*nt + l15, col);
                short8v kh = *(const short8v*)&lds[KHo + o];
                short8v kl = *(const short8v*)&lds[KLo + o];
                sacc[nt] = MFMA(kh, qhf[ks], sacc[nt]);
                sacc[nt] = MFMA(kl, qhf[ks], sacc[nt]);
                sacc[nt] = MFMA(kh, qlf[ks], sacc[nt]);
            }
        }

        // ---- online softmax: reduce over own 16 + l4-group (xor 16,32) ----
        f32x4 sr[4];
        float mx = -INFINITY;
        #pragma unroll
        for (int nt = 0; nt < 4; ++nt) {
            sr[nt] = sacc[nt]*0.125f + addv[nt];
            mx = fmaxf(mx, fmaxf(fmaxf(sr[nt][0], sr[nt][1]), fmaxf(sr[nt][2], sr[nt][3])));
        }
        mx = fmaxf(mx, __shfl_xor(mx, 16));
        mx = fmaxf(mx, __shfl_xor(mx, 32));
        float mn = fmaxf(mrow, mx);
        float al = __expf(mrow - mn);
        float ls = 0.f;
        f32x4 pq[4];
        #pragma unroll
        for (int nt = 0; nt < 4; ++nt) {
            pq[nt][0] = __expf(sr[nt][0] - mn);
            pq[nt][1] = __expf(sr[nt][1] - mn);
            pq[nt][2] = __expf(sr[nt][2] - mn);
            pq[nt][3] = __expf(sr[nt][3] - mn);
            ls += pq[nt][0] + pq[nt][1] + pq[nt][2] + pq[nt][3];
        }
        ls += __shfl_xor(ls, 16);
        ls += __shfl_xor(ls, 32);
        lrow = lrow*al + ls;
        mrow = mn;

        // ---- pack P quads to bf16 hi/lo (in regs) ----
        unsigned ph01[4], ph23[4], pl01[4], pl23[4];
        #pragma unroll
        for (int nt = 0; nt < 4; ++nt)
            pack4(pq[nt][0],pq[nt][1],pq[nt][2],pq[nt][3],
                  ph01[nt],ph23[nt], pl01[nt],pl23[nt]);

        // ---- redistribute P^T -> PV B-frag via shfl_xor within l4-group ----
        short8v pbh[2], pbl[2];
        #pragma unroll
        for (int ks = 0; ks < 2; ++ks) {
            const int loNT = 2*ks, hiNT = 2*ks+1;
            const bool up = (l4 & 2);
            unsigned aH0 = up ? ph01[hiNT] : ph01[loNT];
            unsigned aH1 = up ? ph23[hiNT] : ph23[loNT];
            unsigned aL0 = up ? pl01[hiNT] : pl01[loNT];
            unsigned aL1 = up ? pl23[hiNT] : pl23[loNT];
            unsigned sH0 = up ? ph01[loNT] : ph01[hiNT];
            unsigned sH1 = up ? ph23[loNT] : ph23[hiNT];
            unsigned sL0 = up ? pl01[loNT] : pl01[hiNT];
            unsigned sL1 = up ? pl23[loNT] : pl23[hiNT];
            unsigned x16H0 = __shfl_xor((int)aH0, 16), x16H1 = __shfl_xor((int)aH1, 16);
            unsigned x16L0 = __shfl_xor((int)aL0, 16), x16L1 = __shfl_xor((int)aL1, 16);
            unsigned x32H0 = __shfl_xor((int)sH0, 32), x32H1 = __shfl_xor((int)sH1, 32);
            unsigned x32L0 = __shfl_xor((int)sL0, 32), x32L1 = __shfl_xor((int)sL1, 32);
            unsigned x48H0 = __shfl_xor((int)sH0, 48), x48H1 = __shfl_xor((int)sH1, 48);
            unsigned x48L0 = __shfl_xor((int)sL0, 48), x48L1 = __shfl_xor((int)sL1, 48);
            FragU fh, fl;
            fh.u[0] = (l4==0)?aH0 : (l4==1)?x48H0 : (l4==2)?x32H0 : x16H0;
            fh.u[1] = (l4==0)?aH1 : (l4==1)?x48H1 : (l4==2)?x32H1 : x16H1;
            fh.u[2] = (l4==0)?x16H0 : (l4==1)?x32H0 : (l4==2)?x48H0 : aH0;
            fh.u[3] = (l4==0)?x16H1 : (l4==1)?x32H1 : (l4==2)?x48H1 : aH1;
            fl.u[0] = (l4==0)?aL0 : (l4==1)?x48L0 : (l4==2)?x32L0 : x16L0;
            fl.u[1] = (l4==0)?aL1 : (l4==1)?x48L1 : (l4==2)?x32L1 : x16L1;
            fl.u[2] = (l4==0)?x16L0 : (l4==1)?x32L0 : (l4==2)?x48L0 : aL0;
            fl.u[3] = (l4==0)?x16L1 : (l4==1)?x32L1 : (l4==2)?x48L1 : aL1;
            pbh[ks] = fh.s; pbl[ks] = fl.s;
        }

        // ---- rescale, then PV: O^T[d][q] = Vt x P ----
        #pragma unroll
        for (int dnt = 0; dnt < 4; ++dnt) oacc[dnt] *= al;
        #pragma unroll
        for (int ks = 0; ks < 2; ++ks) {
            const int col = l4*8 + 32*ks;
            #pragma unroll
            for (int dnt = 0; dnt < 4; ++dnt) {
                int o = swz(16*dnt + l15, col);
                short8v vh = *(const short8v*)&lds[VTHo + o];
                short8v vl = *(const short8v*)&lds[VTLo + o];
                oacc[dnt] = MFMA(vh, pbh[ks], oacc[dnt]);
                oacc[dnt] = MFMA(vl, pbh[ks], oacc[dnt]);
                oacc[dnt] = MFMA(vh, pbl[ks], oacc[dnt]);
            }
        }
    }

    // ---- epilogue: lane owns q = 16w + l15, d = 16dnt + 4*l4 + 0..3 ----
    const int q64 = 16*w + l15;
    if (partial) {
        const int rowIdx = (int)(bh*2 + (m ? 1 : 0));
        float* P = ws + ((long)rowIdx*8 + seg) * PS;
        #pragma unroll
        for (int dnt = 0; dnt < 4; ++dnt)
            *(f32x4*)&P[q64*64 + 16*dnt + 4*l4] = oacc[dnt];
        if (l4 == 0) { P[4096 + q64] = mrow; P[4160 + q64] = lrow; }

        // ---- split-K last-arriver merge (replaces second kernel) ----
        __threadfence();
        if (tid == 0) {
            int* cnt = (int*)(ws + CNT_OFF);
            int old = atomicAdd(&cnt[rowIdx], 1);
            lastFlag = (old == 7);
        }
        __syncthreads();
        if (lastFlag) {
            __threadfence();   // acquire other WGs' partials
            const float* base = ws + (long)rowIdx * 8 * PS;
            int q  = tid >> 2;
            int dd = (tid & 3) << 4;
            float msg[8], lsg[8];
            float M = -INFINITY;
            #pragma unroll
            for (int s = 0; s < 8; ++s) {
                msg[s] = base[s*PS + 4096 + q];
                lsg[s] = base[s*PS + 4160 + q];
                M = fmaxf(M, msg[s]);
            }
            float L = 0.f, wv[8];
            #pragma unroll
            for (int s = 0; s < 8; ++s) { wv[s] = __expf(msg[s] - M); L += wv[s]*lsg[s]; }
            int qg = m*64 + q;
            float sc = from_mask[(long)b*S + qg] / L;
            #pragma unroll
            for (int c = 0; c < 4; ++c) {
                float4 o = make_float4(0.f, 0.f, 0.f, 0.f);
                #pragma unroll
                for (int s = 0; s < 8; ++s) {
                    float4 a = *(const float4*)&base[s*PS + q*64 + dd + 4*c];
                    o.x += wv[s]*a.x; o.y += wv[s]*a.y; o.z += wv[s]*a.z; o.w += wv[s]*a.w;
                }
                o.x *= sc; o.y *= sc; o.z *= sc; o.w *= sc;
                *(float4*)&out[((long)((long)b*S + qg)*H + h)*64 + dd + 4*c] = o;
            }
        }
    } else {
        int qg = m*64 + q64;
        float scn = (1.f / lrow) * from_mask[(long)b*S + qg];
        #pragma unroll
        for (int dnt = 0; dnt < 4; ++dnt) {
            f32x4 o = oacc[dnt] * scn;
            *(f32x4*)&out[((long)((long)b*S + qg)*H + h)*64 + 16*dnt + 4*l4] = o;
        }
    }
}

extern "C" void kernel_launch(void* const* d_in, const int* in_sizes, int n_in,
                              void* d_out, int out_size, void* d_ws, size_t ws_size,
                              hipStream_t stream) {
    const float* q   = (const float*)d_in[0];
    const float* k   = (const float*)d_in[1];
    const float* v   = (const float*)d_in[2];
    const float* bm  = (const float*)d_in[3];
    const float* fm  = (const float*)d_in[4];
    const float* tm  = (const float*)d_in[5];
    const float* fbm = (const float*)d_in[6];
    const float* tbm = (const float*)d_in[7];
    const int*   ra  = (const int*)d_in[8];
    float* out = (float*)d_out;
    float* ws  = (float*)d_ws;   // 48*8*PS floats partials + 48 int counters

    hipMemsetAsync((char*)d_ws + (size_t)CNT_OFF*4, 0, 48*sizeof(int), stream);
    bigbird_attn<<<dim3(1872), dim3(256), 0, stream>>>(q, k, v, bm, fm, tm, fbm, tbm, ra, out, ws);
}